// Round 1
// baseline (1142.818 us; speedup 1.0000x reference)
//
#include <hip/hip_runtime.h>
#include <math.h>

#define BATCH 8
#define NATOMS 192
#define HF 32

__device__ __forceinline__ float sigmoid_f(float x){ return 1.0f/(1.0f+expf(-x)); }
__device__ __forceinline__ float silu_f(float x){ return x/(1.0f+expf(-x)); }
__device__ __forceinline__ float softplus_f(float x){ return fmaxf(x,0.0f)+log1pf(expf(-fabsf(x))); }

__device__ __forceinline__ float wave_sum(float v){
  v += __shfl_xor(v, 1);
  v += __shfl_xor(v, 2);
  v += __shfl_xor(v, 4);
  v += __shfl_xor(v, 8);
  v += __shfl_xor(v, 16);
  v += __shfl_xor(v, 32);
  return v;
}

// ---------------- prelude: gamma(t) + pdf embedding, one block per batch ----
__global__ __launch_bounds__(256) void k_prelude(
    const float* __restrict__ pdf, const float* __restrict__ t,
    const float* __restrict__ pdf_w, const float* __restrict__ pdf_b,
    const float* __restrict__ g1w, const float* __restrict__ g1b,
    const float* __restrict__ g2w, const float* __restrict__ g2b,
    const float* __restrict__ g3w, const float* __restrict__ g3b,
    const float* __restrict__ gamma0, const float* __restrict__ gamma1,
    float* __restrict__ temb, float* __restrict__ pdfe)
{
  __shared__ float lds[4];
  const int b = blockIdx.x, tid = threadIdx.x;
  const int wv = tid >> 6, ln = tid & 63;

  // gamma path: gtilde(u) = l1 + pos_lin(sigmoid(pos_lin(l1, w2, b2)), w3, b3)
  const float w1 = softplus_f(g1w[0]);
  const float b1 = g1b[0];
  const float tn = t[b] * (1.0f/1000.0f);
  const float l1_0 = b1;
  const float l1_1 = w1 + b1;
  const float l1_t = fmaf(w1, tn, b1);
  float a0 = 0.f, a1 = 0.f, at = 0.f;
  for (int k = tid; k < 1024; k += 256){
    float w2 = softplus_f(g2w[k]);
    float bb = g2b[k];
    float w3 = softplus_f(g3w[k]);
    a0 += sigmoid_f(fmaf(w2, l1_0, bb)) * w3;
    a1 += sigmoid_f(fmaf(w2, l1_1, bb)) * w3;
    at += sigmoid_f(fmaf(w2, l1_t, bb)) * w3;
  }
  // block reductions (3 values)
  float sums[3]; float vals[3] = {a0, a1, at};
  for (int r = 0; r < 3; ++r){
    float v = wave_sum(vals[r]);
    __syncthreads();
    if (ln == 0) lds[wv] = v;
    __syncthreads();
    sums[r] = lds[0] + lds[1] + lds[2] + lds[3];
  }
  if (tid == 0){
    const float b3 = g3b[0];
    const float g0 = l1_0 + sums[0] + b3;
    const float g1v = l1_1 + sums[1] + b3;
    const float gt = l1_t + sums[2] + b3;
    temb[b] = gamma0[0] + (gamma1[0] - gamma0[0]) * (gt - g0) / (g1v - g0);
  }

  // pdf embedding: 10 outputs of 3000-dot
  for (int o = 0; o < 10; ++o){
    float p = 0.f;
    const float* pb = pdf + b*3000;
    const float* wb = pdf_w + o*3000;
    for (int k = tid; k < 3000; k += 256) p = fmaf(pb[k], wb[k], p);
    p = wave_sum(p);
    __syncthreads();
    if (ln == 0) lds[wv] = p;
    __syncthreads();
    if (tid == 0) pdfe[b*10 + o] = lds[0] + lds[1] + lds[2] + lds[3] + pdf_b[o];
  }
}

// ---------------- embedding: h0 = emb_in([species, t_emb, pdf_emb]) --------
__global__ __launch_bounds__(256) void k_embed(
    const float* __restrict__ xyz, const float* __restrict__ temb,
    const float* __restrict__ pdfe, const float* __restrict__ wi,
    const float* __restrict__ bi, float* __restrict__ h, float* __restrict__ x)
{
  int g = blockIdx.x * 256 + threadIdx.x;
  if (g >= BATCH*NATOMS*HF) return;
  int f = g & 31;
  int node = g >> 5;
  int b = node / NATOMS;
  float sp = xyz[node*4 + 3];
  const float* w = wi + f*12;
  float a = bi[f];
  a = fmaf(sp, w[0], a);
  a = fmaf(temb[b], w[1], a);
  const float* pe = pdfe + b*10;
#pragma unroll
  for (int p = 0; p < 10; ++p) a = fmaf(pe[p], w[2+p], a);
  h[node*32 + f] = a;
  if (f < 3) x[node*3 + f] = xyz[node*4 + f];
}

// ---------------- one EGC layer: block=(i,b), thread=j ----------------------
__global__ __launch_bounds__(192, 2) void k_egc(
    const float* __restrict__ xin, const float* __restrict__ hin,
    const float* __restrict__ xyz,
    float* __restrict__ xout, float* __restrict__ hout,
    const float* __restrict__ lnhg, const float* __restrict__ lnhb,
    const float* __restrict__ lnxg, const float* __restrict__ lnxb,
    const float* __restrict__ e1w, const float* __restrict__ e1b,
    const float* __restrict__ e2w, const float* __restrict__ e2b,
    const float* __restrict__ eiw, const float* __restrict__ eib,
    const float* __restrict__ n1w, const float* __restrict__ n1b,
    const float* __restrict__ n2w, const float* __restrict__ n2b,
    const float* __restrict__ c1w, const float* __restrict__ c1b,
    const float* __restrict__ c2w, const float* __restrict__ c2b,
    const float* __restrict__ c3w, const float* __restrict__ c3b)
{
  __shared__ float s_hi[32];
  __shared__ float s_part[3][32];
  __shared__ float s_xc[3][3];
  __shared__ float s_magg[32];
  __shared__ float s_n1[32];

  const int i = blockIdx.x, b = blockIdx.y, j = threadIdx.x;
  const int base = b * NATOMS;

  // pair geometry (pre-LN x)
  const float* xi_p = xin + (base + i)*3;
  const float* xj_p = xin + (base + j)*3;
  const float xi0 = xi_p[0], xi1 = xi_p[1], xi2 = xi_p[2];
  const float dfx = xi0 - xj_p[0], dfy = xi1 - xj_p[1], dfz = xi2 - xj_p[2];
  const float d2 = dfx*dfx + dfy*dfy + dfz*dfz;
  const float dist = sqrtf(fmaxf(d2, 1e-12f));
  const float* x0i = xyz + (base + i)*4;
  const float* x0j = xyz + (base + j)*4;
  const float q0 = x0i[0]-x0j[0], q1 = x0i[1]-x0j[1], q2 = x0i[2]-x0j[2];
  const float d0 = sqrtf(fmaxf(q0*q0 + q1*q1 + q2*q2, 1e-12f));

  // LayerNorm h_j and h_i (each thread computes both; i is wave-uniform)
  float hj[32], hi[32];
  {
    const float* p = hin + (base + j)*32;
    float m = 0.f;
#pragma unroll
    for (int k = 0; k < 32; ++k){ hj[k] = p[k]; m += hj[k]; }
    m *= (1.0f/32.0f);
    float v = 0.f;
#pragma unroll
    for (int k = 0; k < 32; ++k){ float d = hj[k]-m; v = fmaf(d, d, v); }
    float r = rsqrtf(v*(1.0f/32.0f) + 1e-5f);
#pragma unroll
    for (int k = 0; k < 32; ++k) hj[k] = fmaf((hj[k]-m)*r, lnhg[k], lnhb[k]);
  }
  {
    const float* p = hin + (base + i)*32;
    float m = 0.f;
#pragma unroll
    for (int k = 0; k < 32; ++k){ hi[k] = p[k]; m += hi[k]; }
    m *= (1.0f/32.0f);
    float v = 0.f;
#pragma unroll
    for (int k = 0; k < 32; ++k){ float d = hi[k]-m; v = fmaf(d, d, v); }
    float r = rsqrtf(v*(1.0f/32.0f) + 1e-5f);
#pragma unroll
    for (int k = 0; k < 32; ++k) hi[k] = fmaf((hi[k]-m)*r, lnhg[k], lnhb[k]);
  }
  if (j < 32) s_hi[j] = hi[j];

  // edg1: einp(66) -> 32, silu
  float m1[32];
#pragma unroll
  for (int f = 0; f < 32; ++f){
    const float* w = e1w + f*66;
    float a = e1b[f];
#pragma unroll
    for (int k = 0; k < 32; ++k) a = fmaf(hi[k], w[k], a);
#pragma unroll
    for (int k = 0; k < 32; ++k) a = fmaf(hj[k], w[32+k], a);
    a = fmaf(d2, w[64], a);
    a = fmaf(d0, w[65], a);
    m1[f] = silu_f(a);
  }
  // cor1 (while hi/hj still live)
  float c1[32];
#pragma unroll
  for (int f = 0; f < 32; ++f){
    const float* w = c1w + f*66;
    float a = c1b[f];
#pragma unroll
    for (int k = 0; k < 32; ++k) a = fmaf(hi[k], w[k], a);
#pragma unroll
    for (int k = 0; k < 32; ++k) a = fmaf(hj[k], w[32+k], a);
    a = fmaf(d2, w[64], a);
    a = fmaf(d0, w[65], a);
    c1[f] = silu_f(a);
  }
  // edg2: 32 -> 32, silu
  float m2[32];
#pragma unroll
  for (int f = 0; f < 32; ++f){
    const float* w = e2w + f*32;
    float a = e2b[f];
#pragma unroll
    for (int k = 0; k < 32; ++k) a = fmaf(m1[k], w[k], a);
    m2[f] = silu_f(a);
  }
  // gate e = sigmoid(edgi . m2), zero diagonal
  float eg = eib[0];
#pragma unroll
  for (int k = 0; k < 32; ++k) eg = fmaf(m2[k], eiw[k], eg);
  const float e = (i == j) ? 0.0f : sigmoid_f(eg);
  // m_agg contribution + wave reduce
#pragma unroll
  for (int f = 0; f < 32; ++f) m2[f] = wave_sum(e * m2[f]);
  const int wv = j >> 6, ln = j & 63;
  if (ln == 0){
#pragma unroll
    for (int f = 0; f < 32; ++f) s_part[wv][f] = m2[f];
  }
  // cor2: 32 -> 32, silu; cor3: 32 -> 1
  float c2[32];
#pragma unroll
  for (int f = 0; f < 32; ++f){
    const float* w = c2w + f*32;
    float a = c2b[f];
#pragma unroll
    for (int k = 0; k < 32; ++k) a = fmaf(c1[k], w[k], a);
    c2[f] = silu_f(a);
  }
  float cwv = c3b[0];
#pragma unroll
  for (int k = 0; k < 32; ++k) cwv = fmaf(c2[k], c3w[k], cwv);
  const float s = cwv / (dist + 1.0f);
  float xc0 = wave_sum(s * dfx);
  float xc1 = wave_sum(s * dfy);
  float xc2 = wave_sum(s * dfz);
  if (ln == 0){ s_xc[wv][0] = xc0; s_xc[wv][1] = xc1; s_xc[wv][2] = xc2; }
  __syncthreads();

  // cross-wave combine of m_agg
  if (j < 32) s_magg[j] = s_part[0][j] + s_part[1][j] + s_part[2][j];
  __syncthreads();

  // node MLP: hn = silu(node1([h_ln_i, m_agg])); h_out = h_ln_i + node2(hn)
  if (j < 32){
    const float* w = n1w + j*64;
    float a = n1b[j];
#pragma unroll
    for (int k = 0; k < 32; ++k) a = fmaf(s_hi[k], w[k], a);
#pragma unroll
    for (int k = 0; k < 32; ++k) a = fmaf(s_magg[k], w[32+k], a);
    s_n1[j] = silu_f(a);
  }
  __syncthreads();
  if (j < 32){
    const float* w = n2w + j*32;
    float a = n2b[j];
#pragma unroll
    for (int k = 0; k < 32; ++k) a = fmaf(s_n1[k], w[k], a);
    hout[(base + i)*32 + j] = s_hi[j] + a;
  }
  // x update: x_out = LN(x_i) + sum_j cw * diff/(dist+1)
  if (j < 3){
    float mx = (xi0 + xi1 + xi2) * (1.0f/3.0f);
    float v0 = xi0-mx, v1 = xi1-mx, v2 = xi2-mx;
    float vv = (v0*v0 + v1*v1 + v2*v2) * (1.0f/3.0f);
    float r = rsqrtf(vv + 1e-5f);
    float xv = (j == 0) ? xi0 : ((j == 1) ? xi1 : xi2);
    float xl = fmaf((xv - mx)*r, lnxg[j], lnxb[j]);
    xout[(base + i)*3 + j] = xl + s_xc[0][j] + s_xc[1][j] + s_xc[2][j];
  }
}

// ---------------- epilogue: output heads --------------------------------
__global__ __launch_bounds__(256) void k_final(
    const float* __restrict__ hin, const float* __restrict__ xin,
    const float* __restrict__ xyz,
    const float* __restrict__ how, const float* __restrict__ hob,
    const float* __restrict__ xow, const float* __restrict__ xob,
    float* __restrict__ out)
{
  int g = blockIdx.x * 256 + threadIdx.x;
  if (g >= BATCH*NATOMS) return;
  const float* h = hin + g*32;
  float a = hob[0];
#pragma unroll
  for (int k = 0; k < 32; ++k) a = fmaf(h[k], how[k], a);
  const float* x = xin + g*3;
#pragma unroll
  for (int c = 0; c < 3; ++c){
    float o = xob[c];
    o = fmaf(x[0], xow[c*3+0], o);
    o = fmaf(x[1], xow[c*3+1], o);
    o = fmaf(x[2], xow[c*3+2], o);
    out[g*4 + c] = o - xyz[g*4 + c];
  }
  out[g*4 + 3] = a;
}

extern "C" void kernel_launch(void* const* d_in, const int* in_sizes, int n_in,
                              void* d_out, int out_size, void* d_ws, size_t ws_size,
                              hipStream_t stream)
{
  const float* xyz      = (const float*)d_in[0];
  const float* pdf      = (const float*)d_in[1];
  const float* t        = (const float*)d_in[2];
  const float* emb_in_w = (const float*)d_in[3];
  const float* emb_in_b = (const float*)d_in[4];
  const float* emb_out_w= (const float*)d_in[5];
  const float* emb_out_b= (const float*)d_in[6];
  const float* x_out_w  = (const float*)d_in[7];
  const float* x_out_b  = (const float*)d_in[8];
  const float* pdf_w    = (const float*)d_in[9];
  const float* pdf_b    = (const float*)d_in[10];
  const float* g1w      = (const float*)d_in[11];
  const float* g1b      = (const float*)d_in[12];
  const float* g2w      = (const float*)d_in[13];
  const float* g2b      = (const float*)d_in[14];
  const float* g3w      = (const float*)d_in[15];
  const float* g3b      = (const float*)d_in[16];
  const float* gamma0   = (const float*)d_in[17];
  const float* gamma1   = (const float*)d_in[18];
  const float* lnhg     = (const float*)d_in[19];
  const float* lnhb     = (const float*)d_in[20];
  const float* lnxg     = (const float*)d_in[21];
  const float* lnxb     = (const float*)d_in[22];
  const float* e1w      = (const float*)d_in[23];
  const float* e1b      = (const float*)d_in[24];
  const float* e2w      = (const float*)d_in[25];
  const float* e2b      = (const float*)d_in[26];
  const float* eiw      = (const float*)d_in[27];
  const float* eib      = (const float*)d_in[28];
  const float* n1w      = (const float*)d_in[29];
  const float* n1b      = (const float*)d_in[30];
  const float* n2w      = (const float*)d_in[31];
  const float* n2b      = (const float*)d_in[32];
  const float* c1w      = (const float*)d_in[33];
  const float* c1b      = (const float*)d_in[34];
  const float* c2w      = (const float*)d_in[35];
  const float* c2b      = (const float*)d_in[36];
  const float* c3w      = (const float*)d_in[37];
  const float* c3b      = (const float*)d_in[38];

  float* ws   = (float*)d_ws;
  float* temb = ws;                       // 8
  float* pdfe = ws + 8;                   // 80
  float* h0   = ws + 88;                  // 49152
  float* h1   = h0 + BATCH*NATOMS*32;     // 49152
  float* xb0  = h1 + BATCH*NATOMS*32;     // 4608
  float* xb1  = xb0 + BATCH*NATOMS*3;     // 4608

  k_prelude<<<BATCH, 256, 0, stream>>>(pdf, t, pdf_w, pdf_b,
      g1w, g1b, g2w, g2b, g3w, g3b, gamma0, gamma1, temb, pdfe);
  k_embed<<<(BATCH*NATOMS*HF + 255)/256, 256, 0, stream>>>(
      xyz, temb, pdfe, emb_in_w, emb_in_b, h0, xb0);

  const float* hcur = h0; float* hnext = h1;
  const float* xcur = xb0; float* xnext = xb1;
  for (int l = 0; l < 4; ++l){
    k_egc<<<dim3(NATOMS, BATCH), 192, 0, stream>>>(
        xcur, hcur, xyz, xnext, hnext,
        lnhg + l*32, lnhb + l*32, lnxg + l*3, lnxb + l*3,
        e1w + l*32*66, e1b + l*32, e2w + l*32*32, e2b + l*32,
        eiw + l*32, eib + l,
        n1w + l*32*64, n1b + l*32, n2w + l*32*32, n2b + l*32,
        c1w + l*32*66, c1b + l*32, c2w + l*32*32, c2b + l*32,
        c3w + l*32, c3b + l);
    const float* th = hcur; hcur = hnext; hnext = (float*)th;
    const float* tx = xcur; xcur = xnext; xnext = (float*)tx;
  }

  k_final<<<(BATCH*NATOMS + 255)/256, 256, 0, stream>>>(
      hcur, xcur, xyz, emb_out_w, emb_out_b, x_out_w, x_out_b, (float*)d_out);
}

// Round 2
// 729.475 us; speedup vs baseline: 1.5666x; 1.5666x over previous
//
#include <hip/hip_runtime.h>
#include <math.h>

#define BATCH 8
#define NATOMS 192
#define HF 32

__device__ __forceinline__ float sigmoid_f(float x){ return 1.0f/(1.0f+__expf(-x)); }
__device__ __forceinline__ float silu_f(float x){ return x/(1.0f+__expf(-x)); }
__device__ __forceinline__ float softplus_f(float x){ return fmaxf(x,0.0f)+log1pf(expf(-fabsf(x))); }

__device__ __forceinline__ float wave_sum(float v){
  v += __shfl_xor(v, 1);
  v += __shfl_xor(v, 2);
  v += __shfl_xor(v, 4);
  v += __shfl_xor(v, 8);
  v += __shfl_xor(v, 16);
  v += __shfl_xor(v, 32);
  return v;
}

// ---------------- prelude: gamma(t) + pdf embedding, one block per batch ----
__global__ __launch_bounds__(256) void k_prelude(
    const float* __restrict__ pdf, const float* __restrict__ t,
    const float* __restrict__ pdf_w, const float* __restrict__ pdf_b,
    const float* __restrict__ g1w, const float* __restrict__ g1b,
    const float* __restrict__ g2w, const float* __restrict__ g2b,
    const float* __restrict__ g3w, const float* __restrict__ g3b,
    const float* __restrict__ gamma0, const float* __restrict__ gamma1,
    float* __restrict__ temb, float* __restrict__ pdfe)
{
  __shared__ float lds[4];
  const int b = blockIdx.x, tid = threadIdx.x;
  const int wv = tid >> 6, ln = tid & 63;

  const float w1 = softplus_f(g1w[0]);
  const float b1 = g1b[0];
  const float tn = t[b] * (1.0f/1000.0f);
  const float l1_0 = b1;
  const float l1_1 = w1 + b1;
  const float l1_t = fmaf(w1, tn, b1);
  float a0 = 0.f, a1 = 0.f, at = 0.f;
  for (int k = tid; k < 1024; k += 256){
    float w2 = softplus_f(g2w[k]);
    float bb = g2b[k];
    float w3 = softplus_f(g3w[k]);
    a0 += sigmoid_f(fmaf(w2, l1_0, bb)) * w3;
    a1 += sigmoid_f(fmaf(w2, l1_1, bb)) * w3;
    at += sigmoid_f(fmaf(w2, l1_t, bb)) * w3;
  }
  float sums[3]; float vals[3] = {a0, a1, at};
  for (int r = 0; r < 3; ++r){
    float v = wave_sum(vals[r]);
    __syncthreads();
    if (ln == 0) lds[wv] = v;
    __syncthreads();
    sums[r] = lds[0] + lds[1] + lds[2] + lds[3];
  }
  if (tid == 0){
    const float b3 = g3b[0];
    const float g0 = l1_0 + sums[0] + b3;
    const float g1v = l1_1 + sums[1] + b3;
    const float gt = l1_t + sums[2] + b3;
    temb[b] = gamma0[0] + (gamma1[0] - gamma0[0]) * (gt - g0) / (g1v - g0);
  }

  for (int o = 0; o < 10; ++o){
    float p = 0.f;
    const float* pb = pdf + b*3000;
    const float* wb = pdf_w + o*3000;
    for (int k = tid; k < 3000; k += 256) p = fmaf(pb[k], wb[k], p);
    p = wave_sum(p);
    __syncthreads();
    if (ln == 0) lds[wv] = p;
    __syncthreads();
    if (tid == 0) pdfe[b*10 + o] = lds[0] + lds[1] + lds[2] + lds[3] + pdf_b[o];
  }
}

// ---------------- embedding: h0 = emb_in([species, t_emb, pdf_emb]) --------
__global__ __launch_bounds__(256) void k_embed(
    const float* __restrict__ xyz, const float* __restrict__ temb,
    const float* __restrict__ pdfe, const float* __restrict__ wi,
    const float* __restrict__ bi, float* __restrict__ h, float* __restrict__ x)
{
  int g = blockIdx.x * 256 + threadIdx.x;
  if (g >= BATCH*NATOMS*HF) return;
  int f = g & 31;
  int node = g >> 5;
  int b = node / NATOMS;
  float sp = xyz[node*4 + 3];
  const float* w = wi + f*12;
  float a = bi[f];
  a = fmaf(sp, w[0], a);
  a = fmaf(temb[b], w[1], a);
  const float* pe = pdfe + b*10;
#pragma unroll
  for (int p = 0; p < 10; ++p) a = fmaf(pe[p], w[2+p], a);
  h[node*32 + f] = a;
  if (f < 3) x[node*3 + f] = xyz[node*4 + f];
}

// ---------------- one EGC layer: block=(i,b), thread=j ----------------------
// Register budget plan (peak live): edg1 {hj,m1}=64 -> cor1 {hj,m1,c1}=96
// (hj dies) -> edg2 {m1,c1,m2}=96 (m1 dies) -> reduce (m2 dies) -> cor2
// {c1,c2}=64. Peak ~112 incl. temps => fits 128-VGPR/4-wave tier.
__global__ __launch_bounds__(192, 4) void k_egc(
    const float* __restrict__ xin, const float* __restrict__ hin,
    const float* __restrict__ xyz,
    float* __restrict__ xout, float* __restrict__ hout,
    const float* __restrict__ lnhg, const float* __restrict__ lnhb,
    const float* __restrict__ lnxg, const float* __restrict__ lnxb,
    const float* __restrict__ e1w, const float* __restrict__ e1b,
    const float* __restrict__ e2w, const float* __restrict__ e2b,
    const float* __restrict__ eiw, const float* __restrict__ eib,
    const float* __restrict__ n1w, const float* __restrict__ n1b,
    const float* __restrict__ n2w, const float* __restrict__ n2b,
    const float* __restrict__ c1w, const float* __restrict__ c1b,
    const float* __restrict__ c2w, const float* __restrict__ c2b,
    const float* __restrict__ c3w, const float* __restrict__ c3b)
{
  __shared__ float s_hi[32];
  __shared__ float s_eb[32];   // e1b[f] + sum_k hi_ln[k]*e1w[f][k]
  __shared__ float s_cb[32];   // c1b[f] + sum_k hi_ln[k]*c1w[f][k]
  __shared__ float s_part[3][32];
  __shared__ float s_xc[3][3];
  __shared__ float s_magg[32];
  __shared__ float s_n1[32];

  const int i = blockIdx.x, b = blockIdx.y, j = threadIdx.x;
  const int base = b * NATOMS;

  // pair geometry (pre-LN x, per reference)
  const float* xi_p = xin + (base + i)*3;
  const float* xj_p = xin + (base + j)*3;
  const float xi0 = xi_p[0], xi1 = xi_p[1], xi2 = xi_p[2];
  const float dfx = xi0 - xj_p[0], dfy = xi1 - xj_p[1], dfz = xi2 - xj_p[2];
  const float d2 = dfx*dfx + dfy*dfy + dfz*dfz;
  const float dist = sqrtf(fmaxf(d2, 1e-12f));
  const float* x0i = xyz + (base + i)*4;
  const float* x0j = xyz + (base + j)*4;
  const float q0 = x0i[0]-x0j[0], q1 = x0i[1]-x0j[1], q2 = x0i[2]-x0j[2];
  const float d0 = sqrtf(fmaxf(q0*q0 + q1*q1 + q2*q2, 1e-12f));

  // LayerNorm h_j into registers (each thread: its own j row)
  float hj[32];
  {
    const float* p = hin + (base + j)*32;
    float m = 0.f;
#pragma unroll
    for (int k = 0; k < 32; ++k){ hj[k] = p[k]; m += hj[k]; }
    m *= (1.0f/32.0f);
    float v = 0.f;
#pragma unroll
    for (int k = 0; k < 32; ++k){ float d = hj[k]-m; v = fmaf(d, d, v); }
    float r = rsqrtf(v*(1.0f/32.0f) + 1e-5f);
#pragma unroll
    for (int k = 0; k < 32; ++k) hj[k] = fmaf((hj[k]-m)*r, lnhg[k], lnhb[k]);
  }

  // stage 1a: LN of h_i (block-uniform row), one element per thread j<32
  if (j < 32){
    const float* p = hin + (base + i)*32;
    float m = 0.f;
#pragma unroll
    for (int k = 0; k < 32; ++k) m += p[k];
    m *= (1.0f/32.0f);
    float v = 0.f;
#pragma unroll
    for (int k = 0; k < 32; ++k){ float d = p[k]-m; v = fmaf(d, d, v); }
    float r = rsqrtf(v*(1.0f/32.0f) + 1e-5f);
    s_hi[j] = fmaf((p[j]-m)*r, lnhg[j], lnhb[j]);
  }
  __syncthreads();
  // stage 1b: fold the (block-uniform) h_i contribution of edg1/cor1 into
  // per-f biases — removes hi[] from every pair thread and 32 FMAs/f/pair.
  if (j < 32){
    const float* w = e1w + j*66;
    float a = e1b[j];
#pragma unroll
    for (int k = 0; k < 32; ++k) a = fmaf(s_hi[k], w[k], a);
    s_eb[j] = a;
    const float* wc = c1w + j*66;
    float c = c1b[j];
#pragma unroll
    for (int k = 0; k < 32; ++k) c = fmaf(s_hi[k], wc[k], c);
    s_cb[j] = c;
  }
  __syncthreads();

  // edg1: 32 outs, each 34 FMA (h_j part + d2 + d0), silu
  float m1[32];
#pragma unroll
  for (int f = 0; f < 32; ++f){
    const float* w = e1w + f*66 + 32;
    float a = s_eb[f];
#pragma unroll
    for (int k = 0; k < 32; ++k) a = fmaf(hj[k], w[k], a);
    a = fmaf(d2, w[32], a);
    a = fmaf(d0, w[33], a);
    m1[f] = silu_f(a);
  }
  // cor1 (last use of hj)
  float c1[32];
#pragma unroll
  for (int f = 0; f < 32; ++f){
    const float* w = c1w + f*66 + 32;
    float a = s_cb[f];
#pragma unroll
    for (int k = 0; k < 32; ++k) a = fmaf(hj[k], w[k], a);
    a = fmaf(d2, w[32], a);
    a = fmaf(d0, w[33], a);
    c1[f] = silu_f(a);
  }
  // edg2: 32 -> 32, silu (m1 dies here)
  float m2[32];
#pragma unroll
  for (int f = 0; f < 32; ++f){
    const float* w = e2w + f*32;
    float a = e2b[f];
#pragma unroll
    for (int k = 0; k < 32; ++k) a = fmaf(m1[k], w[k], a);
    m2[f] = silu_f(a);
  }
  // gate e = sigmoid(edgi . m2), zero diagonal; reduce e*m2 across wave
  float eg = eib[0];
#pragma unroll
  for (int k = 0; k < 32; ++k) eg = fmaf(m2[k], eiw[k], eg);
  const float e = (i == j) ? 0.0f : sigmoid_f(eg);
#pragma unroll
  for (int f = 0; f < 32; ++f) m2[f] = wave_sum(e * m2[f]);
  const int wv = j >> 6, ln = j & 63;
  if (ln == 0){
#pragma unroll
    for (int f = 0; f < 32; ++f) s_part[wv][f] = m2[f];
  }
  // cor2: 32 -> 32, silu; cor3: 32 -> 1
  float c2[32];
#pragma unroll
  for (int f = 0; f < 32; ++f){
    const float* w = c2w + f*32;
    float a = c2b[f];
#pragma unroll
    for (int k = 0; k < 32; ++k) a = fmaf(c1[k], w[k], a);
    c2[f] = silu_f(a);
  }
  float cwv = c3b[0];
#pragma unroll
  for (int k = 0; k < 32; ++k) cwv = fmaf(c2[k], c3w[k], cwv);
  const float s = cwv / (dist + 1.0f);
  float xc0 = wave_sum(s * dfx);
  float xc1 = wave_sum(s * dfy);
  float xc2 = wave_sum(s * dfz);
  if (ln == 0){ s_xc[wv][0] = xc0; s_xc[wv][1] = xc1; s_xc[wv][2] = xc2; }
  __syncthreads();

  if (j < 32) s_magg[j] = s_part[0][j] + s_part[1][j] + s_part[2][j];
  __syncthreads();

  // node MLP: hn = silu(node1([h_ln_i, m_agg])); h_out = h_ln_i + node2(hn)
  if (j < 32){
    const float* w = n1w + j*64;
    float a = n1b[j];
#pragma unroll
    for (int k = 0; k < 32; ++k) a = fmaf(s_hi[k], w[k], a);
#pragma unroll
    for (int k = 0; k < 32; ++k) a = fmaf(s_magg[k], w[32+k], a);
    s_n1[j] = silu_f(a);
  }
  __syncthreads();
  if (j < 32){
    const float* w = n2w + j*32;
    float a = n2b[j];
#pragma unroll
    for (int k = 0; k < 32; ++k) a = fmaf(s_n1[k], w[k], a);
    hout[(base + i)*32 + j] = s_hi[j] + a;
  }
  // x update: x_out = LN(x_i) + sum_j cw * diff/(dist+1)
  if (j < 3){
    float mx = (xi0 + xi1 + xi2) * (1.0f/3.0f);
    float v0 = xi0-mx, v1 = xi1-mx, v2 = xi2-mx;
    float vv = (v0*v0 + v1*v1 + v2*v2) * (1.0f/3.0f);
    float r = rsqrtf(vv + 1e-5f);
    float xv = (j == 0) ? xi0 : ((j == 1) ? xi1 : xi2);
    float xl = fmaf((xv - mx)*r, lnxg[j], lnxb[j]);
    xout[(base + i)*3 + j] = xl + s_xc[0][j] + s_xc[1][j] + s_xc[2][j];
  }
}

// ---------------- epilogue: output heads --------------------------------
__global__ __launch_bounds__(256) void k_final(
    const float* __restrict__ hin, const float* __restrict__ xin,
    const float* __restrict__ xyz,
    const float* __restrict__ how, const float* __restrict__ hob,
    const float* __restrict__ xow, const float* __restrict__ xob,
    float* __restrict__ out)
{
  int g = blockIdx.x * 256 + threadIdx.x;
  if (g >= BATCH*NATOMS) return;
  const float* h = hin + g*32;
  float a = hob[0];
#pragma unroll
  for (int k = 0; k < 32; ++k) a = fmaf(h[k], how[k], a);
  const float* x = xin + g*3;
#pragma unroll
  for (int c = 0; c < 3; ++c){
    float o = xob[c];
    o = fmaf(x[0], xow[c*3+0], o);
    o = fmaf(x[1], xow[c*3+1], o);
    o = fmaf(x[2], xow[c*3+2], o);
    out[g*4 + c] = o - xyz[g*4 + c];
  }
  out[g*4 + 3] = a;
}

extern "C" void kernel_launch(void* const* d_in, const int* in_sizes, int n_in,
                              void* d_out, int out_size, void* d_ws, size_t ws_size,
                              hipStream_t stream)
{
  const float* xyz      = (const float*)d_in[0];
  const float* pdf      = (const float*)d_in[1];
  const float* t        = (const float*)d_in[2];
  const float* emb_in_w = (const float*)d_in[3];
  const float* emb_in_b = (const float*)d_in[4];
  const float* emb_out_w= (const float*)d_in[5];
  const float* emb_out_b= (const float*)d_in[6];
  const float* x_out_w  = (const float*)d_in[7];
  const float* x_out_b  = (const float*)d_in[8];
  const float* pdf_w    = (const float*)d_in[9];
  const float* pdf_b    = (const float*)d_in[10];
  const float* g1w      = (const float*)d_in[11];
  const float* g1b      = (const float*)d_in[12];
  const float* g2w      = (const float*)d_in[13];
  const float* g2b      = (const float*)d_in[14];
  const float* g3w      = (const float*)d_in[15];
  const float* g3b      = (const float*)d_in[16];
  const float* gamma0   = (const float*)d_in[17];
  const float* gamma1   = (const float*)d_in[18];
  const float* lnhg     = (const float*)d_in[19];
  const float* lnhb     = (const float*)d_in[20];
  const float* lnxg     = (const float*)d_in[21];
  const float* lnxb     = (const float*)d_in[22];
  const float* e1w      = (const float*)d_in[23];
  const float* e1b      = (const float*)d_in[24];
  const float* e2w      = (const float*)d_in[25];
  const float* e2b      = (const float*)d_in[26];
  const float* eiw      = (const float*)d_in[27];
  const float* eib      = (const float*)d_in[28];
  const float* n1w      = (const float*)d_in[29];
  const float* n1b      = (const float*)d_in[30];
  const float* n2w      = (const float*)d_in[31];
  const float* n2b      = (const float*)d_in[32];
  const float* c1w      = (const float*)d_in[33];
  const float* c1b      = (const float*)d_in[34];
  const float* c2w      = (const float*)d_in[35];
  const float* c2b      = (const float*)d_in[36];
  const float* c3w      = (const float*)d_in[37];
  const float* c3b      = (const float*)d_in[38];

  float* ws   = (float*)d_ws;
  float* temb = ws;                       // 8
  float* pdfe = ws + 8;                   // 80
  float* h0   = ws + 88;
  float* h1   = h0 + BATCH*NATOMS*32;
  float* xb0  = h1 + BATCH*NATOMS*32;
  float* xb1  = xb0 + BATCH*NATOMS*3;

  k_prelude<<<BATCH, 256, 0, stream>>>(pdf, t, pdf_w, pdf_b,
      g1w, g1b, g2w, g2b, g3w, g3b, gamma0, gamma1, temb, pdfe);
  k_embed<<<(BATCH*NATOMS*HF + 255)/256, 256, 0, stream>>>(
      xyz, temb, pdfe, emb_in_w, emb_in_b, h0, xb0);

  const float* hcur = h0; float* hnext = h1;
  const float* xcur = xb0; float* xnext = xb1;
  for (int l = 0; l < 4; ++l){
    k_egc<<<dim3(NATOMS, BATCH), 192, 0, stream>>>(
        xcur, hcur, xyz, xnext, hnext,
        lnhg + l*32, lnhb + l*32, lnxg + l*3, lnxb + l*3,
        e1w + l*32*66, e1b + l*32, e2w + l*32*32, e2b + l*32,
        eiw + l*32, eib + l,
        n1w + l*32*64, n1b + l*32, n2w + l*32*32, n2b + l*32,
        c1w + l*32*66, c1b + l*32, c2w + l*32*32, c2b + l*32,
        c3w + l*32, c3b + l);
    const float* th = hcur; hcur = hnext; hnext = (float*)th;
    const float* tx = xcur; xcur = xnext; xnext = (float*)tx;
  }

  k_final<<<(BATCH*NATOMS + 255)/256, 256, 0, stream>>>(
      hcur, xcur, xyz, emb_out_w, emb_out_b, x_out_w, x_out_b, (float*)d_out);
}

// Round 3
// 491.229 us; speedup vs baseline: 2.3264x; 1.4850x over previous
//
#include <hip/hip_runtime.h>
#include <math.h>

#define BATCH 8
#define NATOMS 192
#define HF 32

__device__ __forceinline__ float sigmoid_f(float x){ return 1.0f/(1.0f+__expf(-x)); }
__device__ __forceinline__ float silu_f(float x){ return x/(1.0f+__expf(-x)); }
__device__ __forceinline__ float softplus_f(float x){ return fmaxf(x,0.0f)+log1pf(expf(-fabsf(x))); }

__device__ __forceinline__ float wave_sum(float v){
  v += __shfl_xor(v, 1);
  v += __shfl_xor(v, 2);
  v += __shfl_xor(v, 4);
  v += __shfl_xor(v, 8);
  v += __shfl_xor(v, 16);
  v += __shfl_xor(v, 32);
  return v;
}

// ---------------- prelude: blocks 0..79 = pdf dot (b,o); 80..87 = gamma(b) --
__global__ __launch_bounds__(256) void k_prelude(
    const float* __restrict__ pdf, const float* __restrict__ t,
    const float* __restrict__ pdf_w, const float* __restrict__ pdf_b,
    const float* __restrict__ g1w, const float* __restrict__ g1b,
    const float* __restrict__ g2w, const float* __restrict__ g2b,
    const float* __restrict__ g3w, const float* __restrict__ g3b,
    const float* __restrict__ gamma0, const float* __restrict__ gamma1,
    float* __restrict__ temb, float* __restrict__ pdfe)
{
  __shared__ float lds[4];
  const int bx = blockIdx.x, tid = threadIdx.x;
  const int wv = tid >> 6, ln = tid & 63;

  if (bx < 80){
    const int b = bx / 10, o = bx % 10;
    const float* pb = pdf + b*3000;
    const float* wb = pdf_w + o*3000;
    float p = 0.f;
    for (int k = tid; k < 3000; k += 256) p = fmaf(pb[k], wb[k], p);
    p = wave_sum(p);
    if (ln == 0) lds[wv] = p;
    __syncthreads();
    if (tid == 0) pdfe[b*10 + o] = lds[0] + lds[1] + lds[2] + lds[3] + pdf_b[o];
    return;
  }
  const int b = bx - 80;
  const float w1 = softplus_f(g1w[0]);
  const float b1 = g1b[0];
  const float tn = t[b] * (1.0f/1000.0f);
  const float l1_0 = b1;
  const float l1_1 = w1 + b1;
  const float l1_t = fmaf(w1, tn, b1);
  float a0 = 0.f, a1 = 0.f, at = 0.f;
  for (int k = tid; k < 1024; k += 256){
    float w2 = softplus_f(g2w[k]);
    float bb = g2b[k];
    float w3 = softplus_f(g3w[k]);
    a0 += sigmoid_f(fmaf(w2, l1_0, bb)) * w3;
    a1 += sigmoid_f(fmaf(w2, l1_1, bb)) * w3;
    at += sigmoid_f(fmaf(w2, l1_t, bb)) * w3;
  }
  float sums[3]; float vals[3] = {a0, a1, at};
  for (int r = 0; r < 3; ++r){
    float v = wave_sum(vals[r]);
    __syncthreads();
    if (ln == 0) lds[wv] = v;
    __syncthreads();
    sums[r] = lds[0] + lds[1] + lds[2] + lds[3];
  }
  if (tid == 0){
    const float b3 = g3b[0];
    const float g0 = l1_0 + sums[0] + b3;
    const float g1v = l1_1 + sums[1] + b3;
    const float gt = l1_t + sums[2] + b3;
    temb[b] = gamma0[0] + (gamma1[0] - gamma0[0]) * (gt - g0) / (g1v - g0);
  }
}

// ---------------- embedding: h0 = emb_in([species, t_emb, pdf_emb]) --------
__global__ __launch_bounds__(256) void k_embed(
    const float* __restrict__ xyz, const float* __restrict__ temb,
    const float* __restrict__ pdfe, const float* __restrict__ wi,
    const float* __restrict__ bi, float* __restrict__ h, float* __restrict__ x)
{
  int g = blockIdx.x * 256 + threadIdx.x;
  if (g >= BATCH*NATOMS*HF) return;
  int f = g & 31;
  int node = g >> 5;
  int b = node / NATOMS;
  float sp = xyz[node*4 + 3];
  const float* w = wi + f*12;
  float a = bi[f];
  a = fmaf(sp, w[0], a);
  a = fmaf(temb[b], w[1], a);
  const float* pe = pdfe + b*10;
#pragma unroll
  for (int p = 0; p < 10; ++p) a = fmaf(pe[p], w[2+p], a);
  h[node*32 + f] = a;
  if (f < 3) x[node*3 + f] = xyz[node*4 + f];
}

// ---------------- one EGC layer: block=(i,b), thread=j ----------------------
// Register discipline: LN'd h rows live in LDS (s_h, padded +1 => conflict-
// free). Each chain re-reads hj from LDS so the two chains never have their
// arrays live simultaneously. Peak per-thread live: 64 floats + temps.
// __launch_bounds__(192,3): VGPR cap ~170 — loose on purpose; round-2 showed
// a tight cap (128) makes the allocator dump the arrays to scratch (91 MB of
// spill writes/dispatch).
__global__ __launch_bounds__(192, 3) void k_egc(
    const float* __restrict__ xin, const float* __restrict__ hin,
    const float* __restrict__ xyz,
    float* __restrict__ xout, float* __restrict__ hout,
    const float* __restrict__ lnhg, const float* __restrict__ lnhb,
    const float* __restrict__ lnxg, const float* __restrict__ lnxb,
    const float* __restrict__ e1w, const float* __restrict__ e1b,
    const float* __restrict__ e2w, const float* __restrict__ e2b,
    const float* __restrict__ eiw, const float* __restrict__ eib,
    const float* __restrict__ n1w, const float* __restrict__ n1b,
    const float* __restrict__ n2w, const float* __restrict__ n2b,
    const float* __restrict__ c1w, const float* __restrict__ c1b,
    const float* __restrict__ c2w, const float* __restrict__ c2b,
    const float* __restrict__ c3w, const float* __restrict__ c3b)
{
  __shared__ float s_h[NATOMS][33];   // LN'd h rows, +1 pad
  __shared__ float s_eb[32];          // e1b[f] + sum_k hi_ln[k]*e1w[f][k]
  __shared__ float s_cb[32];          // c1b[f] + sum_k hi_ln[k]*c1w[f][k]
  __shared__ float s_part[3][32];
  __shared__ float s_xc[3][3];
  __shared__ float s_magg[32];
  __shared__ float s_n1[32];

  const int i = blockIdx.x, b = blockIdx.y, j = threadIdx.x;
  const int base = b * NATOMS;
  const int wv = j >> 6, ln = j & 63;

  // pair geometry (pre-LN x, per reference)
  const float* xi_p = xin + (base + i)*3;
  const float* xj_p = xin + (base + j)*3;
  const float xi0 = xi_p[0], xi1 = xi_p[1], xi2 = xi_p[2];
  const float dfx = xi0 - xj_p[0], dfy = xi1 - xj_p[1], dfz = xi2 - xj_p[2];
  const float d2 = dfx*dfx + dfy*dfy + dfz*dfz;
  const float dist = sqrtf(fmaxf(d2, 1e-12f));
  const float* x0i = xyz + (base + i)*4;
  const float* x0j = xyz + (base + j)*4;
  const float q0 = x0i[0]-x0j[0], q1 = x0i[1]-x0j[1], q2 = x0i[2]-x0j[2];
  const float d0 = sqrtf(fmaxf(q0*q0 + q1*q1 + q2*q2, 1e-12f));

  // LayerNorm own row j -> LDS
  {
    const float* p = hin + (base + j)*32;
    float hj[32];
    float m = 0.f;
#pragma unroll
    for (int k = 0; k < 32; ++k){ hj[k] = p[k]; m += hj[k]; }
    m *= (1.0f/32.0f);
    float v = 0.f;
#pragma unroll
    for (int k = 0; k < 32; ++k){ float d = hj[k]-m; v = fmaf(d, d, v); }
    float r = rsqrtf(v*(1.0f/32.0f) + 1e-5f);
#pragma unroll
    for (int k = 0; k < 32; ++k) s_h[j][k] = fmaf((hj[k]-m)*r, lnhg[k], lnhb[k]);
  }
  __syncthreads();

  // fold block-uniform h_i contribution of edg1/cor1 into per-f biases
  if (j < 32){
    const float* w = e1w + j*66;
    float a = e1b[j];
#pragma unroll
    for (int k = 0; k < 32; ++k) a = fmaf(s_h[i][k], w[k], a);
    s_eb[j] = a;
    const float* wc = c1w + j*66;
    float c = c1b[j];
#pragma unroll
    for (int k = 0; k < 32; ++k) c = fmaf(s_h[i][k], wc[k], c);
    s_cb[j] = c;
  }
  __syncthreads();

  // ---------------- edge chain ----------------
  {
    float hj[32];
#pragma unroll
    for (int k = 0; k < 32; ++k) hj[k] = s_h[j][k];
    float m1[32];
#pragma unroll
    for (int f = 0; f < 32; ++f){
      const float* w = e1w + f*66 + 32;
      float a = s_eb[f];
#pragma unroll
      for (int k = 0; k < 32; ++k) a = fmaf(hj[k], w[k], a);
      a = fmaf(d2, w[32], a);
      a = fmaf(d0, w[33], a);
      m1[f] = silu_f(a);
    }
    // hj dead; edg2: 32 -> 32, silu
    float m2[32];
#pragma unroll
    for (int f = 0; f < 32; ++f){
      const float* w = e2w + f*32;
      float a = e2b[f];
#pragma unroll
      for (int k = 0; k < 32; ++k) a = fmaf(m1[k], w[k], a);
      m2[f] = silu_f(a);
    }
    // gate e = sigmoid(edgi . m2), zero diagonal; reduce e*m2 across wave
    float eg = eib[0];
#pragma unroll
    for (int k = 0; k < 32; ++k) eg = fmaf(m2[k], eiw[k], eg);
    const float e = (i == j) ? 0.0f : sigmoid_f(eg);
#pragma unroll
    for (int f = 0; f < 32; ++f) m2[f] = wave_sum(e * m2[f]);
    if (ln == 0){
#pragma unroll
      for (int f = 0; f < 32; ++f) s_part[wv][f] = m2[f];
    }
  }

  // ---------------- coordinate chain ----------------
  {
    float hj[32];
#pragma unroll
    for (int k = 0; k < 32; ++k) hj[k] = s_h[j][k];
    float c1[32];
#pragma unroll
    for (int f = 0; f < 32; ++f){
      const float* w = c1w + f*66 + 32;
      float a = s_cb[f];
#pragma unroll
      for (int k = 0; k < 32; ++k) a = fmaf(hj[k], w[k], a);
      a = fmaf(d2, w[32], a);
      a = fmaf(d0, w[33], a);
      c1[f] = silu_f(a);
    }
    float c2[32];
#pragma unroll
    for (int f = 0; f < 32; ++f){
      const float* w = c2w + f*32;
      float a = c2b[f];
#pragma unroll
      for (int k = 0; k < 32; ++k) a = fmaf(c1[k], w[k], a);
      c2[f] = silu_f(a);
    }
    float cwv = c3b[0];
#pragma unroll
    for (int k = 0; k < 32; ++k) cwv = fmaf(c2[k], c3w[k], cwv);
    const float s = cwv / (dist + 1.0f);
    float xc0 = wave_sum(s * dfx);
    float xc1 = wave_sum(s * dfy);
    float xc2 = wave_sum(s * dfz);
    if (ln == 0){ s_xc[wv][0] = xc0; s_xc[wv][1] = xc1; s_xc[wv][2] = xc2; }
  }
  __syncthreads();

  if (j < 32) s_magg[j] = s_part[0][j] + s_part[1][j] + s_part[2][j];
  __syncthreads();

  // node MLP: hn = silu(node1([h_ln_i, m_agg])); h_out = h_ln_i + node2(hn)
  if (j < 32){
    const float* w = n1w + j*64;
    float a = n1b[j];
#pragma unroll
    for (int k = 0; k < 32; ++k) a = fmaf(s_h[i][k], w[k], a);
#pragma unroll
    for (int k = 0; k < 32; ++k) a = fmaf(s_magg[k], w[32+k], a);
    s_n1[j] = silu_f(a);
  }
  __syncthreads();
  if (j < 32){
    const float* w = n2w + j*32;
    float a = n2b[j];
#pragma unroll
    for (int k = 0; k < 32; ++k) a = fmaf(s_n1[k], w[k], a);
    hout[(base + i)*32 + j] = s_h[i][j] + a;
  }
  // x update: x_out = LN(x_i) + sum_j cw * diff/(dist+1)
  if (j < 3){
    float mx = (xi0 + xi1 + xi2) * (1.0f/3.0f);
    float v0 = xi0-mx, v1 = xi1-mx, v2 = xi2-mx;
    float vv = (v0*v0 + v1*v1 + v2*v2) * (1.0f/3.0f);
    float r = rsqrtf(vv + 1e-5f);
    float xv = (j == 0) ? xi0 : ((j == 1) ? xi1 : xi2);
    float xl = fmaf((xv - mx)*r, lnxg[j], lnxb[j]);
    xout[(base + i)*3 + j] = xl + s_xc[0][j] + s_xc[1][j] + s_xc[2][j];
  }
}

// ---------------- epilogue: output heads --------------------------------
__global__ __launch_bounds__(256) void k_final(
    const float* __restrict__ hin, const float* __restrict__ xin,
    const float* __restrict__ xyz,
    const float* __restrict__ how, const float* __restrict__ hob,
    const float* __restrict__ xow, const float* __restrict__ xob,
    float* __restrict__ out)
{
  int g = blockIdx.x * 256 + threadIdx.x;
  if (g >= BATCH*NATOMS) return;
  const float* h = hin + g*32;
  float a = hob[0];
#pragma unroll
  for (int k = 0; k < 32; ++k) a = fmaf(h[k], how[k], a);
  const float* x = xin + g*3;
#pragma unroll
  for (int c = 0; c < 3; ++c){
    float o = xob[c];
    o = fmaf(x[0], xow[c*3+0], o);
    o = fmaf(x[1], xow[c*3+1], o);
    o = fmaf(x[2], xow[c*3+2], o);
    out[g*4 + c] = o - xyz[g*4 + c];
  }
  out[g*4 + 3] = a;
}

extern "C" void kernel_launch(void* const* d_in, const int* in_sizes, int n_in,
                              void* d_out, int out_size, void* d_ws, size_t ws_size,
                              hipStream_t stream)
{
  const float* xyz      = (const float*)d_in[0];
  const float* pdf      = (const float*)d_in[1];
  const float* t        = (const float*)d_in[2];
  const float* emb_in_w = (const float*)d_in[3];
  const float* emb_in_b = (const float*)d_in[4];
  const float* emb_out_w= (const float*)d_in[5];
  const float* emb_out_b= (const float*)d_in[6];
  const float* x_out_w  = (const float*)d_in[7];
  const float* x_out_b  = (const float*)d_in[8];
  const float* pdf_w    = (const float*)d_in[9];
  const float* pdf_b    = (const float*)d_in[10];
  const float* g1w      = (const float*)d_in[11];
  const float* g1b      = (const float*)d_in[12];
  const float* g2w      = (const float*)d_in[13];
  const float* g2b      = (const float*)d_in[14];
  const float* g3w      = (const float*)d_in[15];
  const float* g3b      = (const float*)d_in[16];
  const float* gamma0   = (const float*)d_in[17];
  const float* gamma1   = (const float*)d_in[18];
  const float* lnhg     = (const float*)d_in[19];
  const float* lnhb     = (const float*)d_in[20];
  const float* lnxg     = (const float*)d_in[21];
  const float* lnxb     = (const float*)d_in[22];
  const float* e1w      = (const float*)d_in[23];
  const float* e1b      = (const float*)d_in[24];
  const float* e2w      = (const float*)d_in[25];
  const float* e2b      = (const float*)d_in[26];
  const float* eiw      = (const float*)d_in[27];
  const float* eib      = (const float*)d_in[28];
  const float* n1w      = (const float*)d_in[29];
  const float* n1b      = (const float*)d_in[30];
  const float* n2w      = (const float*)d_in[31];
  const float* n2b      = (const float*)d_in[32];
  const float* c1w      = (const float*)d_in[33];
  const float* c1b      = (const float*)d_in[34];
  const float* c2w      = (const float*)d_in[35];
  const float* c2b      = (const float*)d_in[36];
  const float* c3w      = (const float*)d_in[37];
  const float* c3b      = (const float*)d_in[38];

  float* ws   = (float*)d_ws;
  float* temb = ws;                       // 8
  float* pdfe = ws + 8;                   // 80
  float* h0   = ws + 88;
  float* h1   = h0 + BATCH*NATOMS*32;
  float* xb0  = h1 + BATCH*NATOMS*32;
  float* xb1  = xb0 + BATCH*NATOMS*3;

  k_prelude<<<88, 256, 0, stream>>>(pdf, t, pdf_w, pdf_b,
      g1w, g1b, g2w, g2b, g3w, g3b, gamma0, gamma1, temb, pdfe);
  k_embed<<<(BATCH*NATOMS*HF + 255)/256, 256, 0, stream>>>(
      xyz, temb, pdfe, emb_in_w, emb_in_b, h0, xb0);

  const float* hcur = h0; float* hnext = h1;
  const float* xcur = xb0; float* xnext = xb1;
  for (int l = 0; l < 4; ++l){
    k_egc<<<dim3(NATOMS, BATCH), 192, 0, stream>>>(
        xcur, hcur, xyz, xnext, hnext,
        lnhg + l*32, lnhb + l*32, lnxg + l*3, lnxb + l*3,
        e1w + l*32*66, e1b + l*32, e2w + l*32*32, e2b + l*32,
        eiw + l*32, eib + l,
        n1w + l*32*64, n1b + l*32, n2w + l*32*32, n2b + l*32,
        c1w + l*32*66, c1b + l*32, c2w + l*32*32, c2b + l*32,
        c3w + l*32, c3b + l);
    const float* th = hcur; hcur = hnext; hnext = (float*)th;
    const float* tx = xcur; xcur = xnext; xnext = (float*)tx;
  }

  k_final<<<(BATCH*NATOMS + 255)/256, 256, 0, stream>>>(
      hcur, xcur, xyz, emb_out_w, emb_out_b, x_out_w, x_out_b, (float*)d_out);
}

// Round 4
// 394.585 us; speedup vs baseline: 2.8963x; 1.2449x over previous
//
#include <hip/hip_runtime.h>
#include <math.h>

#define BATCH 8
#define NATOMS 192
#define HF 32

__device__ __forceinline__ float sigmoid_f(float x){ return 1.0f/(1.0f+__expf(-x)); }
__device__ __forceinline__ float silu_f(float x){ return x/(1.0f+__expf(-x)); }
__device__ __forceinline__ float softplus_f(float x){ return fmaxf(x,0.0f)+log1pf(expf(-fabsf(x))); }

__device__ __forceinline__ float wave_sum(float v){
  v += __shfl_xor(v, 1);
  v += __shfl_xor(v, 2);
  v += __shfl_xor(v, 4);
  v += __shfl_xor(v, 8);
  v += __shfl_xor(v, 16);
  v += __shfl_xor(v, 32);
  return v;
}

// ---------------- prelude: blocks 0..79 = pdf dot (b,o); 80..87 = gamma(b) --
__global__ __launch_bounds__(256) void k_prelude(
    const float* __restrict__ pdf, const float* __restrict__ t,
    const float* __restrict__ pdf_w, const float* __restrict__ pdf_b,
    const float* __restrict__ g1w, const float* __restrict__ g1b,
    const float* __restrict__ g2w, const float* __restrict__ g2b,
    const float* __restrict__ g3w, const float* __restrict__ g3b,
    const float* __restrict__ gamma0, const float* __restrict__ gamma1,
    float* __restrict__ temb, float* __restrict__ pdfe)
{
  __shared__ float lds[4];
  const int bx = blockIdx.x, tid = threadIdx.x;
  const int wv = tid >> 6, ln = tid & 63;

  if (bx < 80){
    const int b = bx / 10, o = bx % 10;
    const float* pb = pdf + b*3000;
    const float* wb = pdf_w + o*3000;
    float p = 0.f;
    for (int k = tid; k < 3000; k += 256) p = fmaf(pb[k], wb[k], p);
    p = wave_sum(p);
    if (ln == 0) lds[wv] = p;
    __syncthreads();
    if (tid == 0) pdfe[b*10 + o] = lds[0] + lds[1] + lds[2] + lds[3] + pdf_b[o];
    return;
  }
  const int b = bx - 80;
  const float w1 = softplus_f(g1w[0]);
  const float b1 = g1b[0];
  const float tn = t[b] * (1.0f/1000.0f);
  const float l1_0 = b1;
  const float l1_1 = w1 + b1;
  const float l1_t = fmaf(w1, tn, b1);
  float a0 = 0.f, a1 = 0.f, at = 0.f;
  for (int k = tid; k < 1024; k += 256){
    float w2 = softplus_f(g2w[k]);
    float bb = g2b[k];
    float w3 = softplus_f(g3w[k]);
    a0 += sigmoid_f(fmaf(w2, l1_0, bb)) * w3;
    a1 += sigmoid_f(fmaf(w2, l1_1, bb)) * w3;
    at += sigmoid_f(fmaf(w2, l1_t, bb)) * w3;
  }
  float sums[3]; float vals[3] = {a0, a1, at};
  for (int r = 0; r < 3; ++r){
    float v = wave_sum(vals[r]);
    __syncthreads();
    if (ln == 0) lds[wv] = v;
    __syncthreads();
    sums[r] = lds[0] + lds[1] + lds[2] + lds[3];
  }
  if (tid == 0){
    const float b3 = g3b[0];
    const float g0 = l1_0 + sums[0] + b3;
    const float g1v = l1_1 + sums[1] + b3;
    const float gt = l1_t + sums[2] + b3;
    temb[b] = gamma0[0] + (gamma1[0] - gamma0[0]) * (gt - g0) / (g1v - g0);
  }
}

// ---------------- embedding: h0 = emb_in([species, t_emb, pdf_emb]) --------
__global__ __launch_bounds__(256) void k_embed(
    const float* __restrict__ xyz, const float* __restrict__ temb,
    const float* __restrict__ pdfe, const float* __restrict__ wi,
    const float* __restrict__ bi, float* __restrict__ h, float* __restrict__ x)
{
  int g = blockIdx.x * 256 + threadIdx.x;
  if (g >= BATCH*NATOMS*HF) return;
  int f = g & 31;
  int node = g >> 5;
  int b = node / NATOMS;
  float sp = xyz[node*4 + 3];
  const float* w = wi + f*12;
  float a = bi[f];
  a = fmaf(sp, w[0], a);
  a = fmaf(temb[b], w[1], a);
  const float* pe = pdfe + b*10;
#pragma unroll
  for (int p = 0; p < 10; ++p) a = fmaf(pe[p], w[2+p], a);
  h[node*32 + f] = a;
  if (f < 3) x[node*3 + f] = xyz[node*4 + f];
}

// ---------------- per-node precompute (per layer): LN + rank-separable parts
// thread = (node, f). Outputs:
//   hln[node][f]  : LayerNorm'd h
//   vep[node][f]  : e1b[f] + sum_k hln[k]*e1w[f][k]      (i-side, bias folded)
//   ue [node][f]  :          sum_k hln[k]*e1w[f][32+k]   (j-side)
//   vcp/uc        : same for cor1
__global__ __launch_bounds__(256) void k_node(
    const float* __restrict__ hraw,
    const float* __restrict__ lnhg, const float* __restrict__ lnhb,
    const float* __restrict__ e1w, const float* __restrict__ e1b,
    const float* __restrict__ c1w, const float* __restrict__ c1b,
    float* __restrict__ hln, float* __restrict__ ue, float* __restrict__ uc,
    float* __restrict__ vep, float* __restrict__ vcp)
{
  int g = blockIdx.x * 256 + threadIdx.x;
  if (g >= BATCH*NATOMS*32) return;
  const int f = g & 31, node = g >> 5;
  const float* row = hraw + node*32;
  float hl[32];
  float m = 0.f;
#pragma unroll
  for (int k = 0; k < 32; ++k){ hl[k] = row[k]; m += hl[k]; }
  m *= (1.0f/32.0f);
  float v = 0.f;
#pragma unroll
  for (int k = 0; k < 32; ++k){ float d = hl[k]-m; v = fmaf(d, d, v); }
  float r = rsqrtf(v*(1.0f/32.0f) + 1e-5f);
#pragma unroll
  for (int k = 0; k < 32; ++k) hl[k] = fmaf((hl[k]-m)*r, lnhg[k], lnhb[k]);
  hln[node*32 + f] = hl[f];

  const float* we = e1w + f*66;
  float sv = e1b[f], su = 0.f;
#pragma unroll
  for (int k = 0; k < 32; ++k){ sv = fmaf(hl[k], we[k], sv); su = fmaf(hl[k], we[32+k], su); }
  vep[node*32 + f] = sv;
  ue [node*32 + f] = su;

  const float* wc = c1w + f*66;
  float cv = c1b[f], cu = 0.f;
#pragma unroll
  for (int k = 0; k < 32; ++k){ cv = fmaf(hl[k], wc[k], cv); cu = fmaf(hl[k], wc[32+k], cu); }
  vcp[node*32 + f] = cv;
  uc [node*32 + f] = cu;
}

// ---------------- one EGC layer: block=(i,b), 384 threads -------------------
// waves 0-2 (tid 0..191): edge chain, thread = j
// waves 3-5 (tid 192..383): coordinate chain, thread = j
// edg1/cor1 collapse to silu(ve_i[f] + ue_j[f] + d2*w64 + d0*w65) via k_node.
// m_agg reduction via LDS staging (not 192 swizzles).
__global__ __launch_bounds__(384, 2) void k_egc(
    const float* __restrict__ xin, const float* __restrict__ xyz,
    const float* __restrict__ hln, const float* __restrict__ ue,
    const float* __restrict__ uc, const float* __restrict__ vep,
    const float* __restrict__ vcp,
    float* __restrict__ xout, float* __restrict__ hout,
    const float* __restrict__ lnxg, const float* __restrict__ lnxb,
    const float* __restrict__ e1w,
    const float* __restrict__ e2w, const float* __restrict__ e2b,
    const float* __restrict__ eiw, const float* __restrict__ eib,
    const float* __restrict__ n1w, const float* __restrict__ n1b,
    const float* __restrict__ n2w, const float* __restrict__ n2b,
    const float* __restrict__ c1w,
    const float* __restrict__ c2w, const float* __restrict__ c2b,
    const float* __restrict__ c3w, const float* __restrict__ c3b)
{
  __shared__ float s_red[NATOMS][33];   // e*m2 staging, +1 pad
  __shared__ float s_part[12][33];
  __shared__ float s_xc[3][3];
  __shared__ float s_magg[32];
  __shared__ float s_n1[32];

  const int i = blockIdx.x, b = blockIdx.y, tid = threadIdx.x;
  const int half = (tid >= NATOMS) ? 1 : 0;
  const int j = tid - half*NATOMS;
  const int base = b * NATOMS;

  // pair geometry (pre-LN x, per reference)
  const float* xi_p = xin + (base + i)*3;
  const float* xj_p = xin + (base + j)*3;
  const float xi0 = xi_p[0], xi1 = xi_p[1], xi2 = xi_p[2];
  const float dfx = xi0 - xj_p[0], dfy = xi1 - xj_p[1], dfz = xi2 - xj_p[2];
  const float d2 = dfx*dfx + dfy*dfy + dfz*dfz;
  const float dist = sqrtf(fmaxf(d2, 1e-12f));
  const float* x0i = xyz + (base + i)*4;
  const float* x0j = xyz + (base + j)*4;
  const float q0 = x0i[0]-x0j[0], q1 = x0i[1]-x0j[1], q2 = x0i[2]-x0j[2];
  const float d0 = sqrtf(fmaxf(q0*q0 + q1*q1 + q2*q2, 1e-12f));

  if (half == 0){
    // -------- edge chain --------
    float u[32];
    const float4* up = (const float4*)(ue + (base + j)*32);
#pragma unroll
    for (int q = 0; q < 8; ++q) ((float4*)u)[q] = up[q];
    float m1[32];
#pragma unroll
    for (int f = 0; f < 32; ++f){
      // vep[(base+i)*32+f] is wave-uniform -> scalarized
      float a = vep[(base + i)*32 + f] + u[f];
      a = fmaf(d2, e1w[f*66 + 64], a);
      a = fmaf(d0, e1w[f*66 + 65], a);
      m1[f] = silu_f(a);
    }
    float m2[32];
#pragma unroll
    for (int f = 0; f < 32; ++f){
      const float* w = e2w + f*32;
      float a = e2b[f];
#pragma unroll
      for (int k = 0; k < 32; ++k) a = fmaf(m1[k], w[k], a);
      m2[f] = silu_f(a);
    }
    float eg = eib[0];
#pragma unroll
    for (int k = 0; k < 32; ++k) eg = fmaf(m2[k], eiw[k], eg);
    const float e = (i == j) ? 0.0f : sigmoid_f(eg);
#pragma unroll
    for (int f = 0; f < 32; ++f) s_red[j][f] = e * m2[f];
  } else {
    // -------- coordinate chain --------
    float u[32];
    const float4* up = (const float4*)(uc + (base + j)*32);
#pragma unroll
    for (int q = 0; q < 8; ++q) ((float4*)u)[q] = up[q];
    float c1[32];
#pragma unroll
    for (int f = 0; f < 32; ++f){
      float a = vcp[(base + i)*32 + f] + u[f];
      a = fmaf(d2, c1w[f*66 + 64], a);
      a = fmaf(d0, c1w[f*66 + 65], a);
      c1[f] = silu_f(a);
    }
    float c2[32];
#pragma unroll
    for (int f = 0; f < 32; ++f){
      const float* w = c2w + f*32;
      float a = c2b[f];
#pragma unroll
      for (int k = 0; k < 32; ++k) a = fmaf(c1[k], w[k], a);
      c2[f] = silu_f(a);
    }
    float cwv = c3b[0];
#pragma unroll
    for (int k = 0; k < 32; ++k) cwv = fmaf(c2[k], c3w[k], cwv);
    const float s = cwv / (dist + 1.0f);
    float xc0 = wave_sum(s * dfx);
    float xc1 = wave_sum(s * dfy);
    float xc2 = wave_sum(s * dfz);
    const int wv = j >> 6;
    if ((j & 63) == 0){ s_xc[wv][0] = xc0; s_xc[wv][1] = xc1; s_xc[wv][2] = xc2; }
  }
  __syncthreads();

  // m_agg reduction: 12 segments of 16 j's, all 384 threads
  {
    const int f = tid & 31, seg = tid >> 5;
    float a = 0.f;
#pragma unroll
    for (int q = 0; q < 16; ++q) a += s_red[seg*16 + q][f];
    s_part[seg][f] = a;
  }
  __syncthreads();
  if (tid < 32){
    float a = 0.f;
#pragma unroll
    for (int sgi = 0; sgi < 12; ++sgi) a += s_part[sgi][tid];
    s_magg[tid] = a;
  }
  __syncthreads();

  // node MLP: hn = silu(node1([hln_i, m_agg])); h_out = hln_i + node2(hn)
  if (tid < 32){
    const float* w = n1w + tid*64;
    float a = n1b[tid];
    const float* hi = hln + (base + i)*32;
#pragma unroll
    for (int k = 0; k < 32; ++k) a = fmaf(hi[k], w[k], a);
#pragma unroll
    for (int k = 0; k < 32; ++k) a = fmaf(s_magg[k], w[32+k], a);
    s_n1[tid] = silu_f(a);
  }
  __syncthreads();
  if (tid < 32){
    const float* w = n2w + tid*32;
    float a = n2b[tid];
#pragma unroll
    for (int k = 0; k < 32; ++k) a = fmaf(s_n1[k], w[k], a);
    hout[(base + i)*32 + tid] = hln[(base + i)*32 + tid] + a;
  }
  // x update: x_out = LN(x_i) + sum_j cw * diff/(dist+1)
  if (half == 1 && j < 3){
    float mx = (xi0 + xi1 + xi2) * (1.0f/3.0f);
    float v0 = xi0-mx, v1 = xi1-mx, v2 = xi2-mx;
    float vv = (v0*v0 + v1*v1 + v2*v2) * (1.0f/3.0f);
    float r = rsqrtf(vv + 1e-5f);
    float xv = (j == 0) ? xi0 : ((j == 1) ? xi1 : xi2);
    float xl = fmaf((xv - mx)*r, lnxg[j], lnxb[j]);
    xout[(base + i)*3 + j] = xl + s_xc[0][j] + s_xc[1][j] + s_xc[2][j];
  }
}

// ---------------- epilogue: output heads --------------------------------
__global__ __launch_bounds__(256) void k_final(
    const float* __restrict__ hin, const float* __restrict__ xin,
    const float* __restrict__ xyz,
    const float* __restrict__ how, const float* __restrict__ hob,
    const float* __restrict__ xow, const float* __restrict__ xob,
    float* __restrict__ out)
{
  int g = blockIdx.x * 256 + threadIdx.x;
  if (g >= BATCH*NATOMS) return;
  const float* h = hin + g*32;
  float a = hob[0];
#pragma unroll
  for (int k = 0; k < 32; ++k) a = fmaf(h[k], how[k], a);
  const float* x = xin + g*3;
#pragma unroll
  for (int c = 0; c < 3; ++c){
    float o = xob[c];
    o = fmaf(x[0], xow[c*3+0], o);
    o = fmaf(x[1], xow[c*3+1], o);
    o = fmaf(x[2], xow[c*3+2], o);
    out[g*4 + c] = o - xyz[g*4 + c];
  }
  out[g*4 + 3] = a;
}

extern "C" void kernel_launch(void* const* d_in, const int* in_sizes, int n_in,
                              void* d_out, int out_size, void* d_ws, size_t ws_size,
                              hipStream_t stream)
{
  const float* xyz      = (const float*)d_in[0];
  const float* pdf      = (const float*)d_in[1];
  const float* t        = (const float*)d_in[2];
  const float* emb_in_w = (const float*)d_in[3];
  const float* emb_in_b = (const float*)d_in[4];
  const float* emb_out_w= (const float*)d_in[5];
  const float* emb_out_b= (const float*)d_in[6];
  const float* x_out_w  = (const float*)d_in[7];
  const float* x_out_b  = (const float*)d_in[8];
  const float* pdf_w    = (const float*)d_in[9];
  const float* pdf_b    = (const float*)d_in[10];
  const float* g1w      = (const float*)d_in[11];
  const float* g1b      = (const float*)d_in[12];
  const float* g2w      = (const float*)d_in[13];
  const float* g2b      = (const float*)d_in[14];
  const float* g3w      = (const float*)d_in[15];
  const float* g3b      = (const float*)d_in[16];
  const float* gamma0   = (const float*)d_in[17];
  const float* gamma1   = (const float*)d_in[18];
  const float* lnhg     = (const float*)d_in[19];
  const float* lnhb     = (const float*)d_in[20];
  const float* lnxg     = (const float*)d_in[21];
  const float* lnxb     = (const float*)d_in[22];
  const float* e1w      = (const float*)d_in[23];
  const float* e1b      = (const float*)d_in[24];
  const float* e2w      = (const float*)d_in[25];
  const float* e2b      = (const float*)d_in[26];
  const float* eiw      = (const float*)d_in[27];
  const float* eib      = (const float*)d_in[28];
  const float* n1w      = (const float*)d_in[29];
  const float* n1b      = (const float*)d_in[30];
  const float* n2w      = (const float*)d_in[31];
  const float* n2b      = (const float*)d_in[32];
  const float* c1w      = (const float*)d_in[33];
  const float* c1b      = (const float*)d_in[34];
  const float* c2w      = (const float*)d_in[35];
  const float* c2b      = (const float*)d_in[36];
  const float* c3w      = (const float*)d_in[37];
  const float* c3b      = (const float*)d_in[38];

  const int NTOT = BATCH*NATOMS;          // 1536 nodes
  float* ws   = (float*)d_ws;
  float* temb = ws;                        // 8
  float* pdfe = ws + 8;                    // 80  (pad to 96 for 16B alignment)
  float* h0   = ws + 96;
  float* h1   = h0  + NTOT*32;
  float* xb0  = h1  + NTOT*32;
  float* xb1  = xb0 + NTOT*3;
  float* hln  = xb1 + NTOT*3;
  float* ue   = hln + NTOT*32;
  float* uc   = ue  + NTOT*32;
  float* vep  = uc  + NTOT*32;
  float* vcp  = vep + NTOT*32;             // end: ~353k floats ≈ 1.4 MB

  k_prelude<<<88, 256, 0, stream>>>(pdf, t, pdf_w, pdf_b,
      g1w, g1b, g2w, g2b, g3w, g3b, gamma0, gamma1, temb, pdfe);
  k_embed<<<(NTOT*HF + 255)/256, 256, 0, stream>>>(
      xyz, temb, pdfe, emb_in_w, emb_in_b, h0, xb0);

  const float* hcur = h0; float* hnext = h1;
  const float* xcur = xb0; float* xnext = xb1;
  for (int l = 0; l < 4; ++l){
    k_node<<<(NTOT*32 + 255)/256, 256, 0, stream>>>(
        hcur, lnhg + l*32, lnhb + l*32,
        e1w + l*32*66, e1b + l*32, c1w + l*32*66, c1b + l*32,
        hln, ue, uc, vep, vcp);
    k_egc<<<dim3(NATOMS, BATCH), 384, 0, stream>>>(
        xcur, xyz, hln, ue, uc, vep, vcp, xnext, hnext,
        lnxg + l*3, lnxb + l*3,
        e1w + l*32*66, e2w + l*32*32, e2b + l*32,
        eiw + l*32, eib + l,
        n1w + l*32*64, n1b + l*32, n2w + l*32*32, n2b + l*32,
        c1w + l*32*66, c2w + l*32*32, c2b + l*32,
        c3w + l*32, c3b + l);
    const float* th = hcur; hcur = hnext; hnext = (float*)th;
    const float* tx = xcur; xcur = xnext; xnext = (float*)tx;
  }

  k_final<<<(NTOT + 255)/256, 256, 0, stream>>>(
      hcur, xcur, xyz, emb_out_w, emb_out_b, x_out_w, x_out_b, (float*)d_out);
}